// Round 18
// baseline (131.443 us; speedup 1.0000x reference)
//
#include <hip/hip_runtime.h>
#include <stdint.h>

typedef float  f32x4 __attribute__((ext_vector_type(4)));
typedef short  s16x8 __attribute__((ext_vector_type(8)));
typedef unsigned int u32;
typedef unsigned short u16;
typedef unsigned int u32x2 __attribute__((ext_vector_type(2)));

#define HID 768
#define OUTF 128
#define LQ 32
#define LD 256

// pack two f32 -> two bf16 (round-to-nearest, ties away)
__device__ __forceinline__ u32 pk_rna(float lo, float hi) {
    u32 a = __builtin_bit_cast(u32, lo) + 0x8000u;
    u32 b = __builtin_bit_cast(u32, hi) + 0x8000u;
    return __builtin_amdgcn_perm(b, a, 0x07060302u);  // {hi.bf16, lo.bf16}
}
__device__ __forceinline__ u16 f2bf(float x) {
    return (u16)((__builtin_bit_cast(u32, x) + 0x8000u) >> 16);
}
__device__ __forceinline__ s16x8 cvt8(f32x4 lo, f32x4 hi) {
    union { u32 u[4]; s16x8 v; } ua;
    ua.u[0] = pk_rna(lo[0], lo[1]);
    ua.u[1] = pk_rna(lo[2], lo[3]);
    ua.u[2] = pk_rna(hi[0], hi[1]);
    ua.u[3] = pk_rna(hi[2], hi[3]);
    return ua.v;
}

// ---------------- kernel 0: W f32 -> bf16, lane-contiguous MFMA fragment layout ----
__global__ __launch_bounds__(256) void wconv(const float* __restrict__ W,
                                             u32* __restrict__ Wb3d) {
    int t = blockIdx.x * 256 + threadIdx.x;   // dword index 0..49151
    int j2   = t & 3;
    int lane = (t >> 2) & 63;
    int cf   = (t >> 8) & 7;
    int kk   = t >> 11;                       // 0..23
    int l15 = lane & 15, g4 = lane >> 4;
    int f = cf * 16 + l15;
    int k = kk * 32 + g4 * 8 + j2 * 2;
    const float* src = W + (size_t)f * HID + k;
    Wb3d[t] = pk_rna(src[0], src[1]);
}

// ---------------- kernel 1: Q projection + L2 norm -> bf16 ----------------
__global__ __launch_bounds__(256) void qproj(const float* __restrict__ qh,
                                             const u16* __restrict__ Wb3,
                                             u16* __restrict__ Qb) {
    const int b = blockIdx.x;
    const int tid = threadIdx.x;
    const int w = tid >> 6, lane = tid & 63, g = lane >> 4, l15 = lane & 15;

    f32x4 acc[2][2] = {};
    const float* A0 = qh + ((size_t)b * LQ + l15) * HID + g * 8;
    const float* A1 = A0 + 16 * HID;
    const u16* Bp = Wb3 + w * 1024 + lane * 8;   // cf0 = 2w

    for (int kk = 0; kk < 24; ++kk) {
        f32x4 x0 = *(const f32x4*)A0;
        f32x4 x1 = *(const f32x4*)(A0 + 4);
        f32x4 y0 = *(const f32x4*)A1;
        f32x4 y1 = *(const f32x4*)(A1 + 4);
        s16x8 b0 = *(const s16x8*)(Bp);
        s16x8 b1 = *(const s16x8*)(Bp + 512);
        s16x8 a0 = cvt8(x0, x1);
        s16x8 a1 = cvt8(y0, y1);
        acc[0][0] = __builtin_amdgcn_mfma_f32_16x16x32_bf16(a0, b0, acc[0][0], 0, 0, 0);
        acc[0][1] = __builtin_amdgcn_mfma_f32_16x16x32_bf16(a0, b1, acc[0][1], 0, 0, 0);
        acc[1][0] = __builtin_amdgcn_mfma_f32_16x16x32_bf16(a1, b0, acc[1][0], 0, 0, 0);
        acc[1][1] = __builtin_amdgcn_mfma_f32_16x16x32_bf16(a1, b1, acc[1][1], 0, 0, 0);
        A0 += 32; A1 += 32; Bp += 4096;
    }

    __shared__ float part[4][32];
    __shared__ float invl[32];
#pragma unroll
    for (int rf = 0; rf < 2; ++rf)
#pragma unroll
        for (int reg = 0; reg < 4; ++reg) {
            float ss = acc[rf][0][reg] * acc[rf][0][reg] + acc[rf][1][reg] * acc[rf][1][reg];
            ss += __shfl_xor(ss, 1); ss += __shfl_xor(ss, 2);
            ss += __shfl_xor(ss, 4); ss += __shfl_xor(ss, 8);
            if (l15 == 0) part[w][rf * 16 + g * 4 + reg] = ss;
        }
    __syncthreads();
    if (tid < 32) {
        float ss = part[0][tid] + part[1][tid] + part[2][tid] + part[3][tid];
        invl[tid] = 1.f / fmaxf(sqrtf(ss), 1e-12f);
    }
    __syncthreads();
#pragma unroll
    for (int rf = 0; rf < 2; ++rf)
#pragma unroll
        for (int cf = 0; cf < 2; ++cf)
#pragma unroll
            for (int reg = 0; reg < 4; ++reg) {
                int q = rf * 16 + g * 4 + reg;
                int f = w * 32 + cf * 16 + l15;
                Qb[(size_t)b * LQ * OUTF + q * OUTF + f] = f2bf(acc[rf][cf][reg] * invl[q]);
            }
}

// ---------------- kernel 2: fused D-projection + norm + mask + MaxSim --------------
// grid = 256 (docs bid, bid+256), block = 1024 (16 waves, 4 waves/SIMD at <=128 VGPR).
// K-SPLIT: wave (c = w&7, h = w>>3) computes cols [16c,16c+16) x K-half h -> Bf[12]
// (48 VGPR). Partial accs merged via LDS accx: h=1 writes pre-barrier, h=0 sums +
// norm + outb post-barrier (FINISH). TAIL lags one slab, RR over (w&7)==(sb&7).
__global__ __launch_bounds__(1024, 4) void dmax(const float* __restrict__ dh,
                                                const int* __restrict__ ids,
                                                const int* __restrict__ skiplist,
                                                const u16* __restrict__ Wb3,
                                                const u16* __restrict__ Qb,
                                                float* __restrict__ out) {
    const int bid = blockIdx.x;
    const int tid = threadIdx.x;
    const int w = tid >> 6, lane = tid & 63, g4 = lane >> 4, l15 = lane & 15;
    const int c = w & 7, h = w >> 3;
    const int qh_ = h;

    __shared__ __align__(16) u16 stg[2][12288];    // 2 x 24 KB bf16 [16 rows][768], swz
    __shared__ __align__(16) u16 outb[2][2048];    // 2 x 4 KB raw D [16 rows][128], swz
    __shared__ __align__(16) float accx[2][8][64][4]; // 16 KB partial-acc exchange
    __shared__ __align__(16) float nrm[2][16][8];  // [P][row][colgroup]
    __shared__ float red[16][16];                  // per-wave per-q partial maxima
    __shared__ int ms[512];
    __shared__ int sk[64];

    // staging: thread t owns 8B-LDS-units {t, t+1024, t+2048} (3 x ds_write_b64)
#define PADOF(v) (((v) / 192) * 1536 + (((((v) % 192)) * 8) ^ ((((v) / 192) & 7) << 4)))
    const int pad0 = PADOF(tid), pad1 = PADOF(tid + 1024), pad2 = PADOF(tid + 2048);

    const int swz = (l15 & 7) << 4, sw45 = swz & 48, sw6 = swz & 64;
    const int aoffEh = l15 * 1536 + ((g4 * 16) ^ sw45) + sw6 + h * 768;       // + kkp*128
    const int aoffOh = l15 * 1536 + ((g4 * 16) ^ sw45) + 64 - sw6 + h * 768;  // + kkp*128
    const int doffE = l15 * 256 + ((g4 * 16) ^ sw45) + sw6;                   // kq 0,2 (+128)
    const int doffO = l15 * 256 + ((g4 * 16) ^ sw45) + 64 - sw6;              // kq 1,3 (+128)

    f32x4 LA0, LA1, LA2;
    f32x4 accS;
    s16x8 Qr0, Qr1, Qr2, Qr3;
    float rmaxH[4] = {-INFINITY, -INFINITY, -INFINITY, -INFINITY};

#define SLABBASE(sab) ((const char*)dh + (size_t)(bid + (((sab) >> 4) << 8)) * 786432 \
                       + (size_t)((sab) & 15) * 49152)

#define LISSUE(sab) { const char* gb_ = SLABBASE(sab) + 16 * tid; \
    LA0 = *(const f32x4*)(gb_); \
    LA1 = *(const f32x4*)(gb_ + 16384); \
    LA2 = *(const f32x4*)(gb_ + 32768); }

#define WSTORE(P) { char* sb_ = (char*)&stg[P][0]; u32x2 d_; \
    d_[0] = pk_rna(LA0[0], LA0[1]); d_[1] = pk_rna(LA0[2], LA0[3]); \
    *(u32x2*)(sb_ + pad0) = d_; \
    d_[0] = pk_rna(LA1[0], LA1[1]); d_[1] = pk_rna(LA1[2], LA1[3]); \
    *(u32x2*)(sb_ + pad1) = d_; \
    d_[0] = pk_rna(LA2[0], LA2[1]); d_[1] = pk_rna(LA2[2], LA2[3]); \
    *(u32x2*)(sb_ + pad2) = d_; }

#define QLOAD(doc_) { const u16* qp_ = Qb + (size_t)((bid + (doc_) * 256) >> 3) * 4096 \
                      + (qh_ * 16 + l15) * 128 + g4 * 8; \
    Qr0 = *(const s16x8*)(qp_);      Qr1 = *(const s16x8*)(qp_ + 32); \
    Qr2 = *(const s16x8*)(qp_ + 64); Qr3 = *(const s16x8*)(qp_ + 96); }

// partial GEMM: 16 rows x 16 cols (group c) x K-half h; h=1 exports partial acc
#define GEMMN(P, s_) { \
    const char* Ab_ = (const char*)&stg[P][0]; \
    f32x4 ac0_ = {}, ac1_ = {}; \
    _Pragma("unroll") for (int kkp = 0; kkp < 6; ++kkp) { \
        s16x8 ae_ = *(const s16x8*)(Ab_ + aoffEh + kkp * 128); \
        s16x8 ao_ = *(const s16x8*)(Ab_ + aoffOh + kkp * 128); \
        ac0_ = __builtin_amdgcn_mfma_f32_16x16x32_bf16(ae_, Bf[2 * kkp],     ac0_, 0, 0, 0); \
        ac1_ = __builtin_amdgcn_mfma_f32_16x16x32_bf16(ao_, Bf[2 * kkp + 1], ac1_, 0, 0, 0); \
    } \
    accS = ac0_ + ac1_; \
    if (h) *(f32x4*)&accx[(s_) & 1][c][lane][0] = accS; }

// post-barrier: h=0 waves merge partials, compute norms, write raw D to outb
#define FINISH(s_) { if (!h) { \
    f32x4 po_ = *(const f32x4*)&accx[(s_) & 1][c][lane][0]; \
    f32x4 at_ = accS + po_; \
    u16* ob_ = &outb[(s_) & 1][0]; \
    _Pragma("unroll") for (int rg = 0; rg < 4; ++rg) { \
        float ss_ = at_[rg] * at_[rg]; \
        ss_ += __shfl_xor(ss_, 1); ss_ += __shfl_xor(ss_, 2); \
        ss_ += __shfl_xor(ss_, 4); ss_ += __shfl_xor(ss_, 8); \
        if (l15 == 0) nrm[(s_) & 1][g4 * 4 + rg][c] = ss_; \
        int dr_ = g4 * 4 + rg; \
        int of_ = (dr_ * 256 + (c * 16 + l15) * 2) ^ ((dr_ & 7) << 4); \
        *(u16*)((char*)ob_ + of_) = f2bf(at_[rg]); \
    } } }

#define TAIL(sb) { \
    if ((w & 7) == ((sb) & 7)) { \
        const char* Db_ = (const char*)&outb[(sb) & 1][0]; \
        s16x8 d0_ = *(const s16x8*)(Db_ + doffE); \
        s16x8 d1_ = *(const s16x8*)(Db_ + doffO); \
        s16x8 d2_ = *(const s16x8*)(Db_ + doffE + 128); \
        s16x8 d3_ = *(const s16x8*)(Db_ + doffO + 128); \
        f32x4 s2_ = {}; \
        s2_ = __builtin_amdgcn_mfma_f32_16x16x32_bf16(Qr0, d0_, s2_, 0, 0, 0); \
        s2_ = __builtin_amdgcn_mfma_f32_16x16x32_bf16(Qr1, d1_, s2_, 0, 0, 0); \
        s2_ = __builtin_amdgcn_mfma_f32_16x16x32_bf16(Qr2, d2_, s2_, 0, 0, 0); \
        s2_ = __builtin_amdgcn_mfma_f32_16x16x32_bf16(Qr3, d3_, s2_, 0, 0, 0); \
        f32x4 n0_ = *(const f32x4*)&nrm[(sb) & 1][l15][0]; \
        f32x4 n1_ = *(const f32x4*)&nrm[(sb) & 1][l15][4]; \
        float ssv_ = (n0_[0] + n0_[1] + n0_[2] + n0_[3]) \
                   + (n1_[0] + n1_[1] + n1_[2] + n1_[3]); \
        float inv_ = 1.f / fmaxf(sqrtf(ssv_), 1e-12f); \
        int keep_ = ms[(((sb) >> 4) << 8) + (((sb) & 15) << 4) + l15]; \
        _Pragma("unroll") for (int rg = 0; rg < 4; ++rg) { \
            float v_ = keep_ ? s2_[rg] * inv_ : -INFINITY; \
            rmaxH[rg] = fmaxf(rmaxH[rg], v_); } \
    } \
    if (((sb) & 15) == 15) { \
        _Pragma("unroll") for (int rg = 0; rg < 4; ++rg) { \
            float v_ = rmaxH[rg]; \
            v_ = fmaxf(v_, __shfl_xor(v_, 1)); v_ = fmaxf(v_, __shfl_xor(v_, 2)); \
            v_ = fmaxf(v_, __shfl_xor(v_, 4)); v_ = fmaxf(v_, __shfl_xor(v_, 8)); \
            if (l15 == 0) red[w][g4 * 4 + rg] = v_; \
            rmaxH[rg] = -INFINITY; } \
        asm volatile("s_waitcnt lgkmcnt(0)" ::: "memory"); \
        __builtin_amdgcn_s_barrier(); \
        if (tid < 32) { \
            int qh2_ = tid >> 4, qi_ = tid & 15; \
            float m_ = red[qh2_ * 8][qi_]; \
            _Pragma("unroll") for (int jj = 1; jj < 8; ++jj) \
                m_ = fmaxf(m_, red[qh2_ * 8 + jj][qi_]); \
            m_ += __shfl_xor(m_, 1); m_ += __shfl_xor(m_, 2); \
            m_ += __shfl_xor(m_, 4); m_ += __shfl_xor(m_, 8); \
            m_ += __shfl_xor(m_, 16); \
            if (tid == 0) out[bid + (((sb) >> 4) << 8)] = m_ * (1.f / 32.f); } \
        if ((sb) == 15) { QLOAD(1); } \
    } }

#define SLABSTEP(s_, PG_) { \
    GEMMN(PG_, s_); \
    __builtin_amdgcn_sched_barrier(0); \
    if ((s_) + 1 < 32) WSTORE(((s_) + 1) & 1); \
    __builtin_amdgcn_sched_barrier(0); \
    if ((s_) + 2 < 32) LISSUE((s_) + 2); \
    asm volatile("s_waitcnt lgkmcnt(0)" ::: "memory"); \
    __builtin_amdgcn_s_barrier(); \
    FINISH(s_); \
    if ((s_) > 0) TAIL((s_) - 1); }

    // ----- prologue -----
    LISSUE(0);

    s16x8 Bf[12];
#pragma unroll
    for (int kk = 0; kk < 12; ++kk)
        Bf[kk] = *(const s16x8*)(Wb3 + (size_t)((h * 12 + kk) * 8 + c) * 512 + lane * 8);

    if (tid < 64) sk[tid] = skiplist[tid];
    asm volatile("s_waitcnt lgkmcnt(0)" ::: "memory");
    __builtin_amdgcn_s_barrier();
    if (tid < 512) {
        int d_ = tid >> 8, r_ = tid & 255;
        int id_ = ids[(size_t)(bid + d_ * 256) * 256 + r_];
        int keep_ = (id_ != 0);
#pragma unroll
        for (int j = 0; j < 64; ++j) keep_ &= (id_ != sk[j]);
        ms[tid] = keep_;
    }
    WSTORE(0);          // waits for LA (slab 0)
    LISSUE(1);
    QLOAD(0);
    asm volatile("s_waitcnt lgkmcnt(0)" ::: "memory");
    __builtin_amdgcn_s_barrier();   // stg0 + ms visible

    // ----- main loop: 32 slabs (2 docs x 16), 2-buffer, unroll by 2 -----
    for (int j = 0; j < 16; ++j) {
        SLABSTEP(2 * j, 0);
        SLABSTEP(2 * j + 1, 1);
    }

    // ----- epilogue: TAIL(31) needs a barrier after FINISH(31) -----
    asm volatile("s_waitcnt lgkmcnt(0)" ::: "memory");
    __builtin_amdgcn_s_barrier();
    TAIL(31);
}

extern "C" void kernel_launch(void* const* d_in, const int* in_sizes, int n_in,
                              void* d_out, int out_size, void* d_ws, size_t ws_size,
                              hipStream_t stream) {
    const float* q_hidden = (const float*)d_in[0];
    const float* d_hidden = (const float*)d_in[1];
    const int*   d_ids    = (const int*)d_in[2];
    const int*   skiplist = (const int*)d_in[3];
    const float* W        = (const float*)d_in[4];
    float* out = (float*)d_out;

    u16* Wb3 = (u16*)d_ws;                        // 192 KB frag-layout W (bf16)
    u16* Qb  = (u16*)((char*)d_ws + 256 * 1024);  // 512 KB bf16 normalized Q

    wconv<<<192, 256, 0, stream>>>(W, (u32*)Wb3);
    qproj<<<64, 256, 0, stream>>>(q_hidden, Wb3, Qb);
    dmax<<<256, 1024, 0, stream>>>(d_hidden, d_ids, skiplist, Wb3, Qb, out);
}

// Round 19
// 100.296 us; speedup vs baseline: 1.3106x; 1.3106x over previous
//
#include <hip/hip_runtime.h>
#include <stdint.h>

typedef float  f32x4 __attribute__((ext_vector_type(4)));
typedef short  s16x8 __attribute__((ext_vector_type(8)));
typedef unsigned int u32;
typedef unsigned short u16;
typedef unsigned int u32x4 __attribute__((ext_vector_type(4)));

#define HID 768
#define OUTF 128
#define LQ 32
#define LD 256

// pack two f32 -> two bf16 (round-to-nearest, ties away)
__device__ __forceinline__ u32 pk_rna(float lo, float hi) {
    u32 a = __builtin_bit_cast(u32, lo) + 0x8000u;
    u32 b = __builtin_bit_cast(u32, hi) + 0x8000u;
    return __builtin_amdgcn_perm(b, a, 0x07060302u);  // {hi.bf16, lo.bf16}
}
__device__ __forceinline__ u16 f2bf(float x) {
    return (u16)((__builtin_bit_cast(u32, x) + 0x8000u) >> 16);
}
__device__ __forceinline__ s16x8 cvt8(f32x4 lo, f32x4 hi) {
    union { u32 u[4]; s16x8 v; } ua;
    ua.u[0] = pk_rna(lo[0], lo[1]);
    ua.u[1] = pk_rna(lo[2], lo[3]);
    ua.u[2] = pk_rna(hi[0], hi[1]);
    ua.u[3] = pk_rna(hi[2], hi[3]);
    return ua.v;
}

// ---------------- kernel 0: W f32 -> bf16, lane-contiguous MFMA fragment layout ----
__global__ __launch_bounds__(256) void wconv(const float* __restrict__ W,
                                             u32* __restrict__ Wb3d) {
    int t = blockIdx.x * 256 + threadIdx.x;   // dword index 0..49151
    int j2   = t & 3;
    int lane = (t >> 2) & 63;
    int cf   = (t >> 8) & 7;
    int kk   = t >> 11;                       // 0..23
    int l15 = lane & 15, g4 = lane >> 4;
    int f = cf * 16 + l15;
    int k = kk * 32 + g4 * 8 + j2 * 2;
    const float* src = W + (size_t)f * HID + k;
    Wb3d[t] = pk_rna(src[0], src[1]);
}

// ---------------- kernel 1: Q projection + L2 norm -> bf16 ----------------
__global__ __launch_bounds__(256) void qproj(const float* __restrict__ qh,
                                             const u16* __restrict__ Wb3,
                                             u16* __restrict__ Qb) {
    const int b = blockIdx.x;
    const int tid = threadIdx.x;
    const int w = tid >> 6, lane = tid & 63, g = lane >> 4, l15 = lane & 15;

    f32x4 acc[2][2] = {};
    const float* A0 = qh + ((size_t)b * LQ + l15) * HID + g * 8;
    const float* A1 = A0 + 16 * HID;
    const u16* Bp = Wb3 + w * 1024 + lane * 8;   // cf0 = 2w

    for (int kk = 0; kk < 24; ++kk) {
        f32x4 x0 = *(const f32x4*)A0;
        f32x4 x1 = *(const f32x4*)(A0 + 4);
        f32x4 y0 = *(const f32x4*)A1;
        f32x4 y1 = *(const f32x4*)(A1 + 4);
        s16x8 b0 = *(const s16x8*)(Bp);
        s16x8 b1 = *(const s16x8*)(Bp + 512);
        s16x8 a0 = cvt8(x0, x1);
        s16x8 a1 = cvt8(y0, y1);
        acc[0][0] = __builtin_amdgcn_mfma_f32_16x16x32_bf16(a0, b0, acc[0][0], 0, 0, 0);
        acc[0][1] = __builtin_amdgcn_mfma_f32_16x16x32_bf16(a0, b1, acc[0][1], 0, 0, 0);
        acc[1][0] = __builtin_amdgcn_mfma_f32_16x16x32_bf16(a1, b0, acc[1][0], 0, 0, 0);
        acc[1][1] = __builtin_amdgcn_mfma_f32_16x16x32_bf16(a1, b1, acc[1][1], 0, 0, 0);
        A0 += 32; A1 += 32; Bp += 4096;
    }

    __shared__ float part[4][32];
    __shared__ float invl[32];
#pragma unroll
    for (int rf = 0; rf < 2; ++rf)
#pragma unroll
        for (int reg = 0; reg < 4; ++reg) {
            float ss = acc[rf][0][reg] * acc[rf][0][reg] + acc[rf][1][reg] * acc[rf][1][reg];
            ss += __shfl_xor(ss, 1); ss += __shfl_xor(ss, 2);
            ss += __shfl_xor(ss, 4); ss += __shfl_xor(ss, 8);
            if (l15 == 0) part[w][rf * 16 + g * 4 + reg] = ss;
        }
    __syncthreads();
    if (tid < 32) {
        float ss = part[0][tid] + part[1][tid] + part[2][tid] + part[3][tid];
        invl[tid] = 1.f / fmaxf(sqrtf(ss), 1e-12f);
    }
    __syncthreads();
#pragma unroll
    for (int rf = 0; rf < 2; ++rf)
#pragma unroll
        for (int cf = 0; cf < 2; ++cf)
#pragma unroll
            for (int reg = 0; reg < 4; ++reg) {
                int q = rf * 16 + g * 4 + reg;
                int f = w * 32 + cf * 16 + l15;
                Qb[(size_t)b * LQ * OUTF + q * OUTF + f] = f2bf(acc[rf][cf][reg] * invl[q]);
            }
}

// ---------------- kernel 2: fused D-projection + norm + mask + MaxSim --------------
// grid = 256 (docs bid, bid+256), block = 512 (8 waves). Slab = 16 rows.
// SINGLE staging register set; per slab: GEMM(s) -> WSTORE(s+1) -> LISSUE(s+2)
// (LISSUE reuses the SAME registers WSTORE reads, so loads cannot be hoisted
// above the consume -> the vmcnt wait never trails newer loads). 2-buffer LDS.
__global__ __launch_bounds__(512, 2) void dmax(const float* __restrict__ dh,
                                               const int* __restrict__ ids,
                                               const int* __restrict__ skiplist,
                                               const u16* __restrict__ Wb3,
                                               const u16* __restrict__ Qb,
                                               float* __restrict__ out) {
    const int bid = blockIdx.x;
    const int tid = threadIdx.x;
    const int w = tid >> 6, lane = tid & 63, g4 = lane >> 4, l15 = lane & 15;
    const int qh_ = w >> 2;

    __shared__ __align__(16) u16 stg[2][12288];   // 2 x 24 KB bf16 [16 rows][768], swz
    __shared__ __align__(16) u16 outb[2][2048];   // 2 x 4 KB raw D [16 rows][128], swz
    __shared__ __align__(16) float nrm[2][16][8]; // [P][row][wave]
    __shared__ float red[8][16];                  // per-wave per-q partial maxima
    __shared__ int ms[512];
    __shared__ int sk[64];

    // staging: thread t owns bf16 8B-unit pairs (2t,2t+1)+1024i, i=0..2
#define PADOF(v) (((v) / 192) * 1536 + (((((v) % 192)) * 8) ^ ((((v) / 192) & 7) << 4)))
    const int pad0 = PADOF(2 * tid), pad1 = PADOF(2 * tid + 1024), pad2 = PADOF(2 * tid + 2048);

    const int swz = (l15 & 7) << 4, sw45 = swz & 48, sw6 = swz & 64;
    const int aoffE = l15 * 1536 + ((g4 * 16) ^ sw45) + sw6;        // + kkp*128 (even kk)
    const int aoffO = l15 * 1536 + ((g4 * 16) ^ sw45) + 64 - sw6;   // + kkp*128 (odd kk)
    const int doffE = l15 * 256 + ((g4 * 16) ^ sw45) + sw6;         // kq 0,2 (+128)
    const int doffO = l15 * 256 + ((g4 * 16) ^ sw45) + 64 - sw6;    // kq 1,3 (+128)

    f32x4 LA0, LA1, LA2, LA3, LA4, LA5;
    s16x8 Qr0, Qr1, Qr2, Qr3;
    float rmaxH[4] = {-INFINITY, -INFINITY, -INFINITY, -INFINITY};

#define SLABBASE(sab) ((const char*)dh + (size_t)(bid + (((sab) >> 4) << 8)) * 786432 \
                       + (size_t)((sab) & 15) * 49152)

#define LISSUE(sab) { const char* gb_ = SLABBASE(sab) + 32 * tid; \
    LA0 = *(const f32x4*)(gb_);          LA1 = *(const f32x4*)(gb_ + 16); \
    LA2 = *(const f32x4*)(gb_ + 16384);  LA3 = *(const f32x4*)(gb_ + 16400); \
    LA4 = *(const f32x4*)(gb_ + 32768);  LA5 = *(const f32x4*)(gb_ + 32784); }

#define WSTORE(P) { char* sb_ = (char*)&stg[P][0]; u32x4 q_; \
    q_[0] = pk_rna(LA0[0], LA0[1]); q_[1] = pk_rna(LA0[2], LA0[3]); \
    q_[2] = pk_rna(LA1[0], LA1[1]); q_[3] = pk_rna(LA1[2], LA1[3]); \
    *(u32x4*)(sb_ + pad0) = q_; \
    q_[0] = pk_rna(LA2[0], LA2[1]); q_[1] = pk_rna(LA2[2], LA2[3]); \
    q_[2] = pk_rna(LA3[0], LA3[1]); q_[3] = pk_rna(LA3[2], LA3[3]); \
    *(u32x4*)(sb_ + pad1) = q_; \
    q_[0] = pk_rna(LA4[0], LA4[1]); q_[1] = pk_rna(LA4[2], LA4[3]); \
    q_[2] = pk_rna(LA5[0], LA5[1]); q_[3] = pk_rna(LA5[2], LA5[3]); \
    *(u32x4*)(sb_ + pad2) = q_; }

#define QLOAD(doc_) { const u16* qp_ = Qb + (size_t)((bid + (doc_) * 256) >> 3) * 4096 \
                      + (qh_ * 16 + l15) * 128 + g4 * 8; \
    Qr0 = *(const s16x8*)(qp_);      Qr1 = *(const s16x8*)(qp_ + 32); \
    Qr2 = *(const s16x8*)(qp_ + 64); Qr3 = *(const s16x8*)(qp_ + 96); }

#define GEMMN(P, s_) { \
    const char* Ab_ = (const char*)&stg[P][0]; \
    u16* ob_ = &outb[(s_) & 1][0]; \
    f32x4 ac0_ = {}, ac1_ = {}; \
    _Pragma("unroll") for (int kkp = 0; kkp < 12; ++kkp) { \
        s16x8 ae_ = *(const s16x8*)(Ab_ + aoffE + kkp * 128); \
        s16x8 ao_ = *(const s16x8*)(Ab_ + aoffO + kkp * 128); \
        ac0_ = __builtin_amdgcn_mfma_f32_16x16x32_bf16(ae_, Bf[2 * kkp],     ac0_, 0, 0, 0); \
        ac1_ = __builtin_amdgcn_mfma_f32_16x16x32_bf16(ao_, Bf[2 * kkp + 1], ac1_, 0, 0, 0); \
    } \
    f32x4 aG_ = ac0_ + ac1_; \
    _Pragma("unroll") for (int rg = 0; rg < 4; ++rg) { \
        float ss_ = aG_[rg] * aG_[rg]; \
        ss_ += __shfl_xor(ss_, 1); ss_ += __shfl_xor(ss_, 2); \
        ss_ += __shfl_xor(ss_, 4); ss_ += __shfl_xor(ss_, 8); \
        if (l15 == 0) nrm[(s_) & 1][g4 * 4 + rg][w] = ss_; \
        int dr_ = g4 * 4 + rg; \
        int of_ = (dr_ * 256 + (w * 16 + l15) * 2) ^ ((dr_ & 7) << 4); \
        *(u16*)((char*)ob_ + of_) = f2bf(aG_[rg]); \
    } }

#define TAIL(sb) { \
    if ((w & 3) == ((sb) & 3)) { \
        const char* Db_ = (const char*)&outb[(sb) & 1][0]; \
        s16x8 d0_ = *(const s16x8*)(Db_ + doffE); \
        s16x8 d1_ = *(const s16x8*)(Db_ + doffO); \
        s16x8 d2_ = *(const s16x8*)(Db_ + doffE + 128); \
        s16x8 d3_ = *(const s16x8*)(Db_ + doffO + 128); \
        f32x4 s2_ = {}; \
        s2_ = __builtin_amdgcn_mfma_f32_16x16x32_bf16(Qr0, d0_, s2_, 0, 0, 0); \
        s2_ = __builtin_amdgcn_mfma_f32_16x16x32_bf16(Qr1, d1_, s2_, 0, 0, 0); \
        s2_ = __builtin_amdgcn_mfma_f32_16x16x32_bf16(Qr2, d2_, s2_, 0, 0, 0); \
        s2_ = __builtin_amdgcn_mfma_f32_16x16x32_bf16(Qr3, d3_, s2_, 0, 0, 0); \
        f32x4 n0_ = *(const f32x4*)&nrm[(sb) & 1][l15][0]; \
        f32x4 n1_ = *(const f32x4*)&nrm[(sb) & 1][l15][4]; \
        float ssv_ = (n0_[0] + n0_[1] + n0_[2] + n0_[3]) \
                   + (n1_[0] + n1_[1] + n1_[2] + n1_[3]); \
        float inv_ = 1.f / fmaxf(sqrtf(ssv_), 1e-12f); \
        int keep_ = ms[(((sb) >> 4) << 8) + (((sb) & 15) << 4) + l15]; \
        _Pragma("unroll") for (int rg = 0; rg < 4; ++rg) { \
            float v_ = keep_ ? s2_[rg] * inv_ : -INFINITY; \
            rmaxH[rg] = fmaxf(rmaxH[rg], v_); } \
    } \
    if (((sb) & 15) == 15) { \
        _Pragma("unroll") for (int rg = 0; rg < 4; ++rg) { \
            float v_ = rmaxH[rg]; \
            v_ = fmaxf(v_, __shfl_xor(v_, 1)); v_ = fmaxf(v_, __shfl_xor(v_, 2)); \
            v_ = fmaxf(v_, __shfl_xor(v_, 4)); v_ = fmaxf(v_, __shfl_xor(v_, 8)); \
            if (l15 == 0) red[w][g4 * 4 + rg] = v_; \
            rmaxH[rg] = -INFINITY; } \
        asm volatile("s_waitcnt lgkmcnt(0)" ::: "memory"); \
        __builtin_amdgcn_s_barrier(); \
        if (tid < 32) { \
            int qi_ = tid & 15; \
            int base_ = (tid < 16) ? 0 : 4; \
            float m_ = fmaxf(fmaxf(red[base_][qi_], red[base_ + 1][qi_]), \
                             fmaxf(red[base_ + 2][qi_], red[base_ + 3][qi_])); \
            m_ += __shfl_xor(m_, 1); m_ += __shfl_xor(m_, 2); \
            m_ += __shfl_xor(m_, 4); m_ += __shfl_xor(m_, 8); \
            m_ += __shfl_xor(m_, 16); \
            if (tid == 0) out[bid + (((sb) >> 4) << 8)] = m_ * (1.f / 32.f); } \
        if ((sb) == 15) { QLOAD(1); } \
    } }

// GEMM first (ds_reads run while HBM delivers LA); then consume LA (WSTORE);
// then refill LA (LISSUE) — anti-dependence pins the order; sched_barrier
// keeps the compiler from interleaving the phases.
#define SLABSTEP(s_, PG_) { \
    GEMMN(PG_, s_); \
    __builtin_amdgcn_sched_barrier(0); \
    if ((s_) + 1 < 32) WSTORE(((s_) + 1) & 1); \
    __builtin_amdgcn_sched_barrier(0); \
    if ((s_) + 2 < 32) LISSUE((s_) + 2); \
    asm volatile("s_waitcnt lgkmcnt(0)" ::: "memory"); \
    __builtin_amdgcn_s_barrier(); \
    TAIL(s_); }

    // ----- prologue -----
    LISSUE(0);

    s16x8 Bf[24];
#pragma unroll
    for (int kk = 0; kk < 24; ++kk)
        Bf[kk] = *(const s16x8*)(Wb3 + (size_t)(kk * 8 + w) * 512 + lane * 8);

    if (tid < 64) sk[tid] = skiplist[tid];
    asm volatile("s_waitcnt lgkmcnt(0)" ::: "memory");
    __builtin_amdgcn_s_barrier();
    {
        int d_ = tid >> 8, r_ = tid & 255;
        int id_ = ids[(size_t)(bid + d_ * 256) * 256 + r_];
        int keep_ = (id_ != 0);
#pragma unroll
        for (int j = 0; j < 64; ++j) keep_ &= (id_ != sk[j]);
        ms[tid] = keep_;
    }
    WSTORE(0);          // waits for LA (slab 0); Bf/ids newer outstanding: one-time cost
    LISSUE(1);
    QLOAD(0);
    asm volatile("s_waitcnt lgkmcnt(0)" ::: "memory");
    __builtin_amdgcn_s_barrier();   // stg0 + ms visible

    // ----- main loop: 32 slabs (2 docs x 16), 2-buffer, unroll by 2 -----
    for (int j = 0; j < 16; ++j) {
        SLABSTEP(2 * j, 0);
        SLABSTEP(2 * j + 1, 1);
    }
}

extern "C" void kernel_launch(void* const* d_in, const int* in_sizes, int n_in,
                              void* d_out, int out_size, void* d_ws, size_t ws_size,
                              hipStream_t stream) {
    const float* q_hidden = (const float*)d_in[0];
    const float* d_hidden = (const float*)d_in[1];
    const int*   d_ids    = (const int*)d_in[2];
    const int*   skiplist = (const int*)d_in[3];
    const float* W        = (const float*)d_in[4];
    float* out = (float*)d_out;

    u16* Wb3 = (u16*)d_ws;                        // 192 KB frag-layout W (bf16)
    u16* Qb  = (u16*)((char*)d_ws + 256 * 1024);  // 512 KB bf16 normalized Q

    wconv<<<192, 256, 0, stream>>>(W, (u32*)Wb3);
    qproj<<<64, 256, 0, stream>>>(q_hidden, Wb3, Qb);
    dmax<<<256, 512, 0, stream>>>(d_hidden, d_ids, skiplist, Wb3, Qb, out);
}